// Round 10
// baseline (313.973 us; speedup 1.0000x reference)
//
#include <hip/hip_runtime.h>

#define NN 100000
#define NE 800000
#define NBLK 196    // ceil(100000/512): 512-node buckets for the scan
#define EPB2 2048   // edges per k_deg block
#define NPART2 ((NE + EPB2 - 1) / EPB2)   // 391
#define PACKBLK 56  // 224*64 threads / 256

typedef unsigned short ushort_t;
typedef unsigned int uint_t;
typedef __attribute__((ext_vector_type(8))) short short8;
typedef __attribute__((ext_vector_type(4))) float floatx4;

__device__ __forceinline__ float bf2f(ushort_t u) {
    union { unsigned int i; float f; } v; v.i = ((unsigned int)u) << 16; return v.f;
}
__device__ __forceinline__ ushort_t f2bf(float f) {
    union { float f; unsigned int i; } v; v.f = f;
    unsigned int b = v.i + 0x7FFF + ((v.i >> 16) & 1);
    return (ushort_t)(b >> 16);
}
__device__ __forceinline__ uint_t pack2(float a, float b) {
    return (uint_t)f2bf(a) | ((uint_t)f2bf(b) << 16);
}

// ---------------- degree count (global atomics) + bucket totals + fused W pack -------------
__global__ __launch_bounds__(256) void k_deg(const int* __restrict__ dst,
                                             int* __restrict__ bcnt,
                                             int* __restrict__ deg,
                                             const float* __restrict__ W1,
                                             const float* __restrict__ Wmu,
                                             const float* __restrict__ Wls,
                                             uint_t* __restrict__ Wt1g,
                                             uint_t* __restrict__ Wt2g) {
    __shared__ int hist[NBLK];
    const int blk = blockIdx.x, t = threadIdx.x;

    if (blk >= NPART2) {
        // ---- packW tail blocks: 56 blocks x 256 = 224 (mat,n) groups x 64 kp ----
        int lidx = (blk - NPART2) * 256 + t;
        int np = lidx >> 6;            // 0..223
        int kp = lidx & 63;
        int mat = np / 112, n = np - mat * 112;
        int k0 = kp * 2, k1 = k0 + 1;
        float w0 = 0.0f, w1 = 0.0f;
        if (mat == 0) {
            if (n < 100) {
                if (k0 < 100) w0 = W1[k0 * 100 + n];
                if (k1 < 100) w1 = W1[k1 * 100 + n];
            }
            Wt1g[n * 64 + kp] = pack2(w0, w1);
        } else {
            if (n < 50) {
                if (k0 < 100) w0 = Wmu[k0 * 50 + n];
                if (k1 < 100) w1 = Wmu[k1 * 50 + n];
            } else if (n < 100) {
                if (k0 < 100) w0 = Wls[k0 * 50 + (n - 50)];
                if (k1 < 100) w1 = Wls[k1 * 50 + (n - 50)];
            }
            Wt2g[n * 64 + kp] = pack2(w0, w1);
        }
        return;
    }

    const int e0 = blk * EPB2;
    const int e1 = (e0 + EPB2 < NE) ? e0 + EPB2 : NE;

    if (t < NBLK) hist[t] = 0;
    __syncthreads();
    for (int e = e0 + t; e < e1; e += 256) {
        int d = dst[e];
        atomicAdd(&deg[d], 1);          // per-node degree (L2-resident 400KB)
        atomicAdd(&hist[d >> 9], 1);    // per-bucket total (LDS)
    }
    __syncthreads();
    if (t < NBLK) {
        int h = hist[t];
        if (h > 0) atomicAdd(&bcnt[t], h);
    }
}

// ---------------- per-bucket scan of deg -> off/cur/dis (base = prefix of bcnt) ------------
__global__ __launch_bounds__(256) void k_scan(const int* __restrict__ bcnt,
                                              const int* __restrict__ deg,
                                              float* __restrict__ dis,
                                              int* __restrict__ off,
                                              int* __restrict__ cur) {
    __shared__ int sc[2][512];
    __shared__ int red[4];
    const int b = blockIdx.x, t = threadIdx.x;
    const int g0 = b * 512;

    // base = sum bcnt[0..b)  (b <= 195 < 256, thread t holds bcnt[t] iff t < b)
    int part = (t < b) ? bcnt[t] : 0;
    #pragma unroll
    for (int o = 32; o > 0; o >>= 1) part += __shfl_down(part, o, 64);
    if ((t & 63) == 0) red[t >> 6] = part;

    int d0 = (g0 + t < NN) ? deg[g0 + t] : 0;
    int d1 = (g0 + t + 256 < NN) ? deg[g0 + t + 256] : 0;
    sc[0][t] = d0;
    sc[0][t + 256] = d1;
    __syncthreads();

    int c = 0;
    for (int o = 1; o < 512; o <<= 1) {
        int nxt = c ^ 1;
        #pragma unroll
        for (int q = 0; q < 2; ++q) {
            int j = t + q * 256;
            sc[nxt][j] = sc[c][j] + ((j >= o) ? sc[c][j - o] : 0);
        }
        c = nxt;
        __syncthreads();
    }

    const int base0 = red[0] + red[1] + red[2] + red[3];
    #pragma unroll
    for (int q = 0; q < 2; ++q) {
        int j = t + q * 256, g = g0 + j;
        int ov = base0 + ((j > 0) ? sc[c][j - 1] : 0);
        if (g < NN) {
            int dv = (q == 0) ? d0 : d1;
            dis[g] = rsqrtf((float)dv + 1.0f);
            off[g] = ov;
            cur[g] = ov;
        } else if (g == NN) {
            off[g] = ov;   // = NE
        }
    }
}

// ---------------- direct CSR place: one random scatter pass ----------------
__global__ __launch_bounds__(256) void k_place2(const int* __restrict__ src,
                                                const int* __restrict__ dst,
                                                int* __restrict__ cur,
                                                int* __restrict__ ssrc) {
    const int stride = gridDim.x * 256;
    for (int e = blockIdx.x * 256 + threadIdx.x; e < NE; e += stride) {
        int d = dst[e];
        int pos = atomicAdd(&cur[d], 1);
        ssrc[pos] = src[e];
    }
}

// ---------------- MFMA GEMM 1: H1' = bf16((X @ W1) * dis), stride 128, pads zeroed ----------
__global__ __launch_bounds__(256) void k_gemm1_mfma(
    const float* __restrict__ X, const uint_t* __restrict__ Wtg,
    const float* __restrict__ dis,
    ushort_t* __restrict__ H)
{
    __shared__ ushort_t Ws[112 * 136];   // 30.5 KB
    const int tid = threadIdx.x;
    const int row0 = blockIdx.x * 64;

    for (int idx = tid; idx < 112 * 16; idx += 256) {
        int n = idx >> 4, c = idx & 15;
        uint4 v = *(const uint4*)&Wtg[n * 64 + c * 4];
        *(uint4*)&Ws[n * 136 + c * 8] = v;
    }
    __syncthreads();

    const int wave = tid >> 6, lane = tid & 63;
    const int quad = lane >> 4, l16 = lane & 15;
    int row = row0 + wave * 16 + l16;
    if (row >= NN) row = NN - 1;
    const float* xp = X + (size_t)row * 100;

    floatx4 acc[7];
    #pragma unroll
    for (int t = 0; t < 7; ++t) acc[t] = (floatx4){0.f, 0.f, 0.f, 0.f};

    #pragma unroll
    for (int ks = 0; ks < 4; ++ks) {
        const int kb = ks * 32 + quad * 8;
        short8 af;
        if (ks < 3) {
            float4 u = *(const float4*)&xp[kb];
            float4 v = *(const float4*)&xp[kb + 4];
            af[0] = (short)f2bf(u.x); af[1] = (short)f2bf(u.y);
            af[2] = (short)f2bf(u.z); af[3] = (short)f2bf(u.w);
            af[4] = (short)f2bf(v.x); af[5] = (short)f2bf(v.y);
            af[6] = (short)f2bf(v.z); af[7] = (short)f2bf(v.w);
        } else {
            af = (short8){0, 0, 0, 0, 0, 0, 0, 0};
            if (quad == 0) {
                float4 u = *(const float4*)&xp[96];
                af[0] = (short)f2bf(u.x); af[1] = (short)f2bf(u.y);
                af[2] = (short)f2bf(u.z); af[3] = (short)f2bf(u.w);
            }
        }
        #pragma unroll
        for (int t = 0; t < 7; ++t) {
            short8 bf = *(const short8*)&Ws[(t * 16 + l16) * 136 + kb];
            acc[t] = __builtin_amdgcn_mfma_f32_16x16x32_bf16(af, bf, acc[t], 0, 0, 0);
        }
    }

    const int mbase = row0 + wave * 16 + quad * 4;
    #pragma unroll
    for (int reg = 0; reg < 4; ++reg) {
        int m = mbase + reg;
        if (m >= NN) continue;
        float dd = dis[m];
        #pragma unroll
        for (int t = 0; t < 7; ++t) {
            int n = t * 16 + l16;
            H[(size_t)m * 128 + n] = (n < 100) ? f2bf(acc[t][reg] * dd) : (ushort_t)0;
        }
        H[(size_t)m * 128 + 112 + l16] = 0;
    }
}

// ---------------- MFMA GEMM 2: out = A2 @ [Wmu|Wls] + [bmu|bls], A stride 128 -------------
__global__ __launch_bounds__(256) void k_gemm2_mfma(
    const ushort_t* __restrict__ A,   // bf16, stride 128, k-padded w/ zeros
    const uint_t* __restrict__ Wtg,
    const float* __restrict__ bmu, const float* __restrict__ bls,
    float* __restrict__ outmu, float* __restrict__ outls)
{
    __shared__ ushort_t Ws[112 * 136];
    const int tid = threadIdx.x;
    const int row0 = blockIdx.x * 64;

    for (int idx = tid; idx < 112 * 16; idx += 256) {
        int n = idx >> 4, c = idx & 15;
        uint4 v = *(const uint4*)&Wtg[n * 64 + c * 4];
        *(uint4*)&Ws[n * 136 + c * 8] = v;
    }
    __syncthreads();

    const int wave = tid >> 6, lane = tid & 63;
    const int quad = lane >> 4, l16 = lane & 15;
    int arow = row0 + wave * 16 + l16;
    if (arow >= NN) arow = NN - 1;

    floatx4 acc[7];
    #pragma unroll
    for (int t = 0; t < 7; ++t) acc[t] = (floatx4){0.f, 0.f, 0.f, 0.f};

    #pragma unroll
    for (int k0 = 0; k0 < 128; k0 += 32) {
        short8 af = *(const short8*)&A[(size_t)arow * 128 + k0 + quad * 8];
        #pragma unroll
        for (int t = 0; t < 7; ++t) {
            short8 bf = *(const short8*)&Ws[(t * 16 + l16) * 136 + k0 + quad * 8];
            acc[t] = __builtin_amdgcn_mfma_f32_16x16x32_bf16(af, bf, acc[t], 0, 0, 0);
        }
    }

    const int mbase = row0 + wave * 16 + quad * 4;
    #pragma unroll
    for (int reg = 0; reg < 4; ++reg) {
        int m = mbase + reg;
        if (m >= NN) continue;
        #pragma unroll
        for (int t = 0; t < 7; ++t) {
            int n = t * 16 + l16;
            if (n < 50) {
                outmu[(size_t)m * 50 + n] = acc[t][reg] + bmu[n];
            } else if (n < 100) {
                outls[(size_t)m * 50 + (n - 50)] = acc[t][reg] + bls[n - 50];
            }
        }
    }
}

// ---------------- aggregation (round-2 proven form: 8 threads/node, stride-128 rows) -------
// val = dis[node] * (H'[node] + sum_e H'[src])
// PHASE 1: store bf16(relu(val + b1) * dis[node])   PHASE 2: store bf16(val)
template<int PHASE>
__global__ __launch_bounds__(256) void k_agg(
    const ushort_t* __restrict__ Hin,
    const int* __restrict__ off, const int* __restrict__ ssrc,
    const float* __restrict__ dis, const float* __restrict__ bias,
    ushort_t* __restrict__ outb)
{
    int i = blockIdx.x * 256 + threadIdx.x;
    if (i >= NN * 8) return;
    int node = i >> 3;
    int col = (i & 7) * 16;

    float a[16];
    {
        short8 u = *(const short8*)(Hin + (size_t)node * 128 + col);
        short8 v = *(const short8*)(Hin + (size_t)node * 128 + col + 8);
        #pragma unroll
        for (int j = 0; j < 8; ++j) { a[j] = bf2f((ushort_t)u[j]); a[8 + j] = bf2f((ushort_t)v[j]); }
    }

    int e0 = off[node], e1 = off[node + 1];
    int e = e0;
    for (; e + 3 < e1; e += 4) {
        int s0 = ssrc[e], s1 = ssrc[e + 1], s2 = ssrc[e + 2], s3 = ssrc[e + 3];
        short8 u0 = *(const short8*)(Hin + (size_t)s0 * 128 + col);
        short8 v0 = *(const short8*)(Hin + (size_t)s0 * 128 + col + 8);
        short8 u1 = *(const short8*)(Hin + (size_t)s1 * 128 + col);
        short8 v1 = *(const short8*)(Hin + (size_t)s1 * 128 + col + 8);
        short8 u2 = *(const short8*)(Hin + (size_t)s2 * 128 + col);
        short8 v2 = *(const short8*)(Hin + (size_t)s2 * 128 + col + 8);
        short8 u3 = *(const short8*)(Hin + (size_t)s3 * 128 + col);
        short8 v3 = *(const short8*)(Hin + (size_t)s3 * 128 + col + 8);
        #pragma unroll
        for (int j = 0; j < 8; ++j) {
            a[j]     += bf2f((ushort_t)u0[j]) + bf2f((ushort_t)u1[j])
                      + bf2f((ushort_t)u2[j]) + bf2f((ushort_t)u3[j]);
            a[8 + j] += bf2f((ushort_t)v0[j]) + bf2f((ushort_t)v1[j])
                      + bf2f((ushort_t)v2[j]) + bf2f((ushort_t)v3[j]);
        }
    }
    for (; e < e1; ++e) {
        int s0 = ssrc[e];
        short8 u0 = *(const short8*)(Hin + (size_t)s0 * 128 + col);
        short8 v0 = *(const short8*)(Hin + (size_t)s0 * 128 + col + 8);
        #pragma unroll
        for (int j = 0; j < 8; ++j) {
            a[j] += bf2f((ushort_t)u0[j]);
            a[8 + j] += bf2f((ushort_t)v0[j]);
        }
    }

    float d = dis[node];
    short8 o0, o1;
    if (PHASE == 1) {
        float b[16];
        #pragma unroll
        for (int j = 0; j < 16; ++j) {
            int cj = col + j;
            b[j] = (cj < 100) ? bias[cj] : 0.0f;
        }
        #pragma unroll
        for (int j = 0; j < 8; ++j) {
            float h0 = fmaxf(a[j] * d + b[j], 0.0f) * d;
            float h1 = fmaxf(a[8 + j] * d + b[8 + j], 0.0f) * d;
            o0[j] = (short)f2bf(h0);
            o1[j] = (short)f2bf(h1);
        }
    } else {
        #pragma unroll
        for (int j = 0; j < 8; ++j) {
            o0[j] = (short)f2bf(a[j] * d);
            o1[j] = (short)f2bf(a[8 + j] * d);
        }
    }
    *(short8*)(outb + (size_t)node * 128 + col) = o0;
    *(short8*)(outb + (size_t)node * 128 + col + 8) = o1;
}

extern "C" void kernel_launch(void* const* d_in, const int* in_sizes, int n_in,
                              void* d_out, int out_size, void* d_ws, size_t ws_size,
                              hipStream_t stream)
{
    const float* x   = (const float*)d_in[0];
    const int*   ei  = (const int*)d_in[1];
    const float* W1  = (const float*)d_in[2];
    const float* b1  = (const float*)d_in[3];
    const float* Wmu = (const float*)d_in[4];
    const float* bmu = (const float*)d_in[5];
    const float* Wls = (const float*)d_in[6];
    const float* bls = (const float*)d_in[7];
    float* out = (float*)d_out;

    const int* src = ei;
    const int* dst = ei + NE;

    // workspace layout (4B element offsets)
    int*   wsI  = (int*)d_ws;
    float* wsF  = (float*)d_ws;
    int*      bcnt = wsI;                          // 196 (pad 256), zeroed w/ deg
    int*      deg  = wsI + 256;                    // 100000  -> 100256
    int*      off  = wsI + 100256;                 // 100001  -> pad 200320
    int*      cur  = wsI + 200320;                 // 100000  -> 300320
    float*    dis  = wsF + 300320;                 // 100000  -> 400320
    uint_t*   Wt1g = (uint_t*)(wsI + 400320);      // 7168    -> 407488
    uint_t*   Wt2g = (uint_t*)(wsI + 407488);      // 7168    -> 414656
    int*      ssrc = wsI + 414656;                 // 800000  -> 1214656
    ushort_t* H1b  = (ushort_t*)(wsI + 1214656);   // 100000*128 bf16 = 6.4M ints -> 7614656
    ushort_t* hb   = (ushort_t*)(wsI + 7614656);   // 6.4M ints -> 14014656
    ushort_t* A2b  = (ushort_t*)(wsI + 14014656);  // 6.4M ints -> 20414656
    (void)ws_size;

    hipMemsetAsync(wsI, 0, (256 + NN) * sizeof(int), stream);   // bcnt + deg
    k_deg<<<NPART2 + PACKBLK, 256, 0, stream>>>(dst, bcnt, deg,
                                                W1, Wmu, Wls, Wt1g, Wt2g);
    k_scan<<<NBLK, 256, 0, stream>>>(bcnt, deg, dis, off, cur);
    k_place2<<<1024, 256, 0, stream>>>(src, dst, cur, ssrc);

    const int gblk = (NN + 63) / 64;
    const int ablk = (NN * 8 + 255) / 256;
    // layer 1: H1' = bf16(X@W1 * dis) ; hb = bf16(relu(dis*(sum H1') + b1) * dis)
    k_gemm1_mfma<<<gblk, 256, 0, stream>>>(x, Wt1g, dis, H1b);
    k_agg<1><<<ablk, 256, 0, stream>>>(H1b, off, ssrc, dis, b1, hb);
    // layer 2: A2 = bf16(dis*(sum hb)) ; out = A2@[Wmu|Wls] + bias
    k_agg<2><<<ablk, 256, 0, stream>>>(hb, off, ssrc, dis, b1, A2b);
    k_gemm2_mfma<<<gblk, 256, 0, stream>>>(A2b, Wt2g, bmu, bls,
                                           out, out + (size_t)NN * 50);
}

// Round 13
// 246.657 us; speedup vs baseline: 1.2729x; 1.2729x over previous
//
#include <hip/hip_runtime.h>

#define NN 100000
#define NE 800000
#define NBLK 196    // ceil(100000/512): scan blocks AND dst-buckets (512 nodes each)
#define BCAP 6144   // bucket capacity (mean 4081, sigma ~64)
#define EPB 8192    // edges per k_part block
#define NPART ((NE + EPB - 1) / EPB)   // 98
#define PACKBLK 56  // 224*64 threads / 256

typedef unsigned short ushort_t;
typedef unsigned int uint_t;
typedef __attribute__((ext_vector_type(8))) short short8;
typedef __attribute__((ext_vector_type(4))) float floatx4;

__device__ __forceinline__ float bf2f(ushort_t u) {
    union { unsigned int i; float f; } v; v.i = ((unsigned int)u) << 16; return v.f;
}
__device__ __forceinline__ ushort_t f2bf(float f) {
    union { float f; unsigned int i; } v; v.f = f;
    unsigned int b = v.i + 0x7FFF + ((v.i >> 16) & 1);
    return (ushort_t)(b >> 16);
}
__device__ __forceinline__ uint_t pack2(float a, float b) {
    return (uint_t)f2bf(a) | ((uint_t)f2bf(b) << 16);
}

// ---------------- partition edges into 196 dst-buckets (+ fused one-shot W pack) ------------
// record = src | (dstLocal<<17)   (src < 2^17, dstLocal < 512)
__global__ __launch_bounds__(256) void k_part(const int* __restrict__ src,
                                              const int* __restrict__ dst,
                                              int* __restrict__ bcnt,
                                              int* __restrict__ bedge,
                                              const float* __restrict__ W1,
                                              const float* __restrict__ Wmu,
                                              const float* __restrict__ Wls,
                                              uint_t* __restrict__ Wt1g,
                                              uint_t* __restrict__ Wt2g) {
    __shared__ int hist[NBLK];
    __shared__ int lbase[NBLK];
    const int blk = blockIdx.x, t = threadIdx.x;

    if (blk >= NPART) {
        // ---- packW tail blocks: 56 blocks x 256 = 224 (mat,n) groups x 64 kp ----
        int lidx = (blk - NPART) * 256 + t;
        int np = lidx >> 6;            // 0..223
        int kp = lidx & 63;
        int mat = np / 112, n = np - mat * 112;
        int k0 = kp * 2, k1 = k0 + 1;
        float w0 = 0.0f, w1 = 0.0f;
        if (mat == 0) {
            if (n < 100) {
                if (k0 < 100) w0 = W1[k0 * 100 + n];
                if (k1 < 100) w1 = W1[k1 * 100 + n];
            }
            Wt1g[n * 64 + kp] = pack2(w0, w1);
        } else {
            if (n < 50) {
                if (k0 < 100) w0 = Wmu[k0 * 50 + n];
                if (k1 < 100) w1 = Wmu[k1 * 50 + n];
            } else if (n < 100) {
                if (k0 < 100) w0 = Wls[k0 * 50 + (n - 50)];
                if (k1 < 100) w1 = Wls[k1 * 50 + (n - 50)];
            }
            Wt2g[n * 64 + kp] = pack2(w0, w1);
        }
        return;
    }

    const int e0 = blk * EPB;
    const int e1 = (e0 + EPB < NE) ? e0 + EPB : NE;

    if (t < NBLK) hist[t] = 0;
    __syncthreads();
    for (int e = e0 + t; e < e1; e += 256)
        atomicAdd(&hist[dst[e] >> 9], 1);
    __syncthreads();
    if (t < NBLK) {
        int h = hist[t];
        lbase[t] = (h > 0) ? atomicAdd(&bcnt[t], h) : 0;
    }
    __syncthreads();
    if (t < NBLK) hist[t] = lbase[t];   // reuse as cursor
    __syncthreads();
    for (int e = e0 + t; e < e1; e += 256) {
        int d = dst[e];
        int b = d >> 9;
        int pos = atomicAdd(&hist[b], 1);
        bedge[b * BCAP + pos] = src[e] | ((d & 511) << 17);
    }
}

// ---------------- fused per-bucket build: hist + base + scan + dis/off + place -------------
__global__ __launch_bounds__(256) void k_build(const int* __restrict__ bcnt,
                                               const int* __restrict__ bedge,
                                               float* __restrict__ dis,
                                               int* __restrict__ off,
                                               int* __restrict__ ssrc) {
    __shared__ int eb[BCAP];       // 24 KB: bucket edges staged once
    __shared__ int hist[512];      // degree hist, later place cursors
    __shared__ int sc[2][512];     // scan ping-pong
    __shared__ int red[4];
    const int b = blockIdx.x, t = threadIdx.x;
    const int cnt = bcnt[b];
    const int* be = bedge + (size_t)b * BCAP;
    const int g0 = b * 512;

    hist[t] = 0; hist[t + 256] = 0;
    // base = sum bcnt[0..b)  (b <= 195 < 256, so thread t holds bcnt[t] iff t < b)
    int part = (t < b) ? bcnt[t] : 0;
    #pragma unroll
    for (int o = 32; o > 0; o >>= 1) part += __shfl_down(part, o, 64);
    if ((t & 63) == 0) red[t >> 6] = part;
    __syncthreads();

    // stage edges to LDS + degree histogram in one pass over bedge
    for (int i = t; i < cnt; i += 256) {
        int v = be[i];
        eb[i] = v;
        atomicAdd(&hist[v >> 17], 1);
    }
    __syncthreads();
    const int base0 = red[0] + red[1] + red[2] + red[3];

    // inclusive scan of 512 degrees
    sc[0][t] = hist[t];
    sc[0][t + 256] = hist[t + 256];
    __syncthreads();
    int c = 0;
    for (int o = 1; o < 512; o <<= 1) {
        int nxt = c ^ 1;
        #pragma unroll
        for (int q = 0; q < 2; ++q) {
            int j = t + q * 256;
            sc[nxt][j] = sc[c][j] + ((j >= o) ? sc[c][j - o] : 0);
        }
        c = nxt;
        __syncthreads();
    }

    // emit dis + off, init place cursors (hist[j] exclusively owned by this thread)
    #pragma unroll
    for (int q = 0; q < 2; ++q) {
        int j = t + q * 256, g = g0 + j;
        int o = base0 + ((j > 0) ? sc[c][j - 1] : 0);
        if (g < NN) dis[g] = rsqrtf((float)hist[j] + 1.0f);
        if (g <= NN) off[g] = o;
        hist[j] = o;
    }
    __syncthreads();

    // place edges from LDS into contiguous CSR region
    for (int i = t; i < cnt; i += 256) {
        int v = eb[i];
        int pos = atomicAdd(&hist[v >> 17], 1);
        ssrc[pos] = v & 0x1FFFF;
    }
}

// ---------------- MFMA GEMM 1: H1' = bf16((X @ W1) * dis), stride 128, pads zeroed ----------
__global__ __launch_bounds__(256) void k_gemm1_mfma(
    const float* __restrict__ X, const uint_t* __restrict__ Wtg,
    const float* __restrict__ dis,
    ushort_t* __restrict__ H)
{
    __shared__ ushort_t Ws[112 * 136];   // 30.5 KB
    const int tid = threadIdx.x;
    const int row0 = blockIdx.x * 64;

    for (int idx = tid; idx < 112 * 16; idx += 256) {
        int n = idx >> 4, c = idx & 15;
        uint4 v = *(const uint4*)&Wtg[n * 64 + c * 4];
        *(uint4*)&Ws[n * 136 + c * 8] = v;
    }
    __syncthreads();

    const int wave = tid >> 6, lane = tid & 63;
    const int quad = lane >> 4, l16 = lane & 15;
    int row = row0 + wave * 16 + l16;
    if (row >= NN) row = NN - 1;
    const float* xp = X + (size_t)row * 100;

    floatx4 acc[7];
    #pragma unroll
    for (int t = 0; t < 7; ++t) acc[t] = (floatx4){0.f, 0.f, 0.f, 0.f};

    #pragma unroll
    for (int ks = 0; ks < 4; ++ks) {
        const int kb = ks * 32 + quad * 8;
        short8 af;
        if (ks < 3) {
            float4 u = *(const float4*)&xp[kb];
            float4 v = *(const float4*)&xp[kb + 4];
            af[0] = (short)f2bf(u.x); af[1] = (short)f2bf(u.y);
            af[2] = (short)f2bf(u.z); af[3] = (short)f2bf(u.w);
            af[4] = (short)f2bf(v.x); af[5] = (short)f2bf(v.y);
            af[6] = (short)f2bf(v.z); af[7] = (short)f2bf(v.w);
        } else {
            af = (short8){0, 0, 0, 0, 0, 0, 0, 0};
            if (quad == 0) {
                float4 u = *(const float4*)&xp[96];
                af[0] = (short)f2bf(u.x); af[1] = (short)f2bf(u.y);
                af[2] = (short)f2bf(u.z); af[3] = (short)f2bf(u.w);
            }
        }
        #pragma unroll
        for (int t = 0; t < 7; ++t) {
            short8 bf = *(const short8*)&Ws[(t * 16 + l16) * 136 + kb];
            acc[t] = __builtin_amdgcn_mfma_f32_16x16x32_bf16(af, bf, acc[t], 0, 0, 0);
        }
    }

    const int mbase = row0 + wave * 16 + quad * 4;
    #pragma unroll
    for (int reg = 0; reg < 4; ++reg) {
        int m = mbase + reg;
        if (m >= NN) continue;
        float dd = dis[m];
        #pragma unroll
        for (int t = 0; t < 7; ++t) {
            int n = t * 16 + l16;
            H[(size_t)m * 128 + n] = (n < 100) ? f2bf(acc[t][reg] * dd) : (ushort_t)0;
        }
        H[(size_t)m * 128 + 112 + l16] = 0;
    }
}

// ---------------- aggregation phase 1 (round-2 proven form: 8 threads/node) ----------------
// val = dis[node] * (H'[node] + sum_e H'[src]);  store bf16(relu(val + b1) * dis[node])
__global__ __launch_bounds__(256) void k_agg1(
    const ushort_t* __restrict__ Hin,
    const int* __restrict__ off, const int* __restrict__ ssrc,
    const float* __restrict__ dis, const float* __restrict__ bias,
    ushort_t* __restrict__ outb)
{
    int i = blockIdx.x * 256 + threadIdx.x;
    if (i >= NN * 8) return;
    int node = i >> 3;
    int col = (i & 7) * 16;

    float a[16];
    {
        short8 u = *(const short8*)(Hin + (size_t)node * 128 + col);
        short8 v = *(const short8*)(Hin + (size_t)node * 128 + col + 8);
        #pragma unroll
        for (int j = 0; j < 8; ++j) { a[j] = bf2f((ushort_t)u[j]); a[8 + j] = bf2f((ushort_t)v[j]); }
    }

    int e0 = off[node], e1 = off[node + 1];
    int e = e0;
    for (; e + 3 < e1; e += 4) {
        int s0 = ssrc[e], s1 = ssrc[e + 1], s2 = ssrc[e + 2], s3 = ssrc[e + 3];
        short8 u0 = *(const short8*)(Hin + (size_t)s0 * 128 + col);
        short8 v0 = *(const short8*)(Hin + (size_t)s0 * 128 + col + 8);
        short8 u1 = *(const short8*)(Hin + (size_t)s1 * 128 + col);
        short8 v1 = *(const short8*)(Hin + (size_t)s1 * 128 + col + 8);
        short8 u2 = *(const short8*)(Hin + (size_t)s2 * 128 + col);
        short8 v2 = *(const short8*)(Hin + (size_t)s2 * 128 + col + 8);
        short8 u3 = *(const short8*)(Hin + (size_t)s3 * 128 + col);
        short8 v3 = *(const short8*)(Hin + (size_t)s3 * 128 + col + 8);
        #pragma unroll
        for (int j = 0; j < 8; ++j) {
            a[j]     += bf2f((ushort_t)u0[j]) + bf2f((ushort_t)u1[j])
                      + bf2f((ushort_t)u2[j]) + bf2f((ushort_t)u3[j]);
            a[8 + j] += bf2f((ushort_t)v0[j]) + bf2f((ushort_t)v1[j])
                      + bf2f((ushort_t)v2[j]) + bf2f((ushort_t)v3[j]);
        }
    }
    for (; e < e1; ++e) {
        int s0 = ssrc[e];
        short8 u0 = *(const short8*)(Hin + (size_t)s0 * 128 + col);
        short8 v0 = *(const short8*)(Hin + (size_t)s0 * 128 + col + 8);
        #pragma unroll
        for (int j = 0; j < 8; ++j) {
            a[j] += bf2f((ushort_t)u0[j]);
            a[8 + j] += bf2f((ushort_t)v0[j]);
        }
    }

    float d = dis[node];
    short8 o0, o1;
    float b[16];
    #pragma unroll
    for (int j = 0; j < 16; ++j) {
        int cj = col + j;
        b[j] = (cj < 100) ? bias[cj] : 0.0f;
    }
    #pragma unroll
    for (int j = 0; j < 8; ++j) {
        float h0 = fmaxf(a[j] * d + b[j], 0.0f) * d;
        float h1 = fmaxf(a[8 + j] * d + b[8 + j], 0.0f) * d;
        o0[j] = (short)f2bf(h0);
        o1[j] = (short)f2bf(h1);
    }
    *(short8*)(outb + (size_t)node * 128 + col) = o0;
    *(short8*)(outb + (size_t)node * 128 + col + 8) = o1;
}

// ---------------- FUSED agg2 + gemm2: gather A2 rows into LDS, then MFMA ----------------
// Block owns 64 nodes. Gather: 4 threads/node x 32 cols -> As[64][136] (bf16, pad-136).
// Then: out = As @ [Wmu|Wls] + [bmu|bls]  (identical MFMA epilogue to old gemm2).
__global__ __launch_bounds__(256) void k_fuse2(
    const ushort_t* __restrict__ Hin,   // hb (complete)
    const int* __restrict__ off, const int* __restrict__ ssrc,
    const float* __restrict__ dis,
    const uint_t* __restrict__ Wtg,
    const float* __restrict__ bmu, const float* __restrict__ bls,
    float* __restrict__ outmu, float* __restrict__ outls)
{
    __shared__ ushort_t Ws[112 * 136];   // 30.5 KB
    __shared__ ushort_t As[64][136];     // 17 KB, pad kills MFMA-read bank conflicts
    const int tid = threadIdx.x;
    const int row0 = blockIdx.x * 64;

    for (int idx = tid; idx < 112 * 16; idx += 256) {
        int n = idx >> 4, c = idx & 15;
        uint4 v = *(const uint4*)&Wtg[n * 64 + c * 4];
        *(uint4*)&Ws[n * 136 + c * 8] = v;
    }

    // ---- gather phase: thread = (local node lr = tid>>2, part = tid&3) ----
    {
        const int lr = tid >> 2;
        const int part = tid & 3;
        const int c0 = part * 32;
        int nd = row0 + lr;
        if (nd >= NN) nd = NN - 1;             // duplicate last row; out-write is guarded
        const ushort_t* selfp = Hin + (size_t)nd * 128 + c0;

        float a[32];
        #pragma unroll
        for (int g = 0; g < 4; ++g) {
            short8 u = *(const short8*)(selfp + g * 8);
            #pragma unroll
            for (int j = 0; j < 8; ++j) a[g * 8 + j] = bf2f((ushort_t)u[j]);
        }

        const int e0v = off[nd], e1v = off[nd + 1];
        int e = e0v;
        for (; e + 1 < e1v; e += 2) {
            int s0 = ssrc[e], s1 = ssrc[e + 1];
            const ushort_t* p0 = Hin + (size_t)s0 * 128 + c0;
            const ushort_t* p1 = Hin + (size_t)s1 * 128 + c0;
            short8 u[4], v[4];
            #pragma unroll
            for (int g = 0; g < 4; ++g) {
                u[g] = *(const short8*)(p0 + g * 8);
                v[g] = *(const short8*)(p1 + g * 8);
            }
            #pragma unroll
            for (int g = 0; g < 4; ++g) {
                #pragma unroll
                for (int j = 0; j < 8; ++j)
                    a[g * 8 + j] += bf2f((ushort_t)u[g][j]) + bf2f((ushort_t)v[g][j]);
            }
        }
        for (; e < e1v; ++e) {
            int s0 = ssrc[e];
            const ushort_t* p0 = Hin + (size_t)s0 * 128 + c0;
            #pragma unroll
            for (int g = 0; g < 4; ++g) {
                short8 u = *(const short8*)(p0 + g * 8);
                #pragma unroll
                for (int j = 0; j < 8; ++j) a[g * 8 + j] += bf2f((ushort_t)u[j]);
            }
        }

        const float d = dis[nd];
        #pragma unroll
        for (int g = 0; g < 4; ++g) {
            short8 o;
            #pragma unroll
            for (int j = 0; j < 8; ++j) o[j] = (short)f2bf(a[g * 8 + j] * d);
            *(short8*)&As[lr][c0 + g * 8] = o;
        }
    }
    __syncthreads();

    // ---- MFMA phase (old gemm2, af from LDS) ----
    const int wave = tid >> 6, lane = tid & 63;
    const int quad = lane >> 4, l16 = lane & 15;
    const int lrow = wave * 16 + l16;

    floatx4 acc[7];
    #pragma unroll
    for (int t = 0; t < 7; ++t) acc[t] = (floatx4){0.f, 0.f, 0.f, 0.f};

    #pragma unroll
    for (int k0 = 0; k0 < 128; k0 += 32) {
        short8 af = *(const short8*)&As[lrow][k0 + quad * 8];
        #pragma unroll
        for (int t = 0; t < 7; ++t) {
            short8 bf = *(const short8*)&Ws[(t * 16 + l16) * 136 + k0 + quad * 8];
            acc[t] = __builtin_amdgcn_mfma_f32_16x16x32_bf16(af, bf, acc[t], 0, 0, 0);
        }
    }

    const int mbase = row0 + wave * 16 + quad * 4;
    #pragma unroll
    for (int reg = 0; reg < 4; ++reg) {
        int m = mbase + reg;
        if (m >= NN) continue;
        #pragma unroll
        for (int t = 0; t < 7; ++t) {
            int n = t * 16 + l16;
            if (n < 50) {
                outmu[(size_t)m * 50 + n] = acc[t][reg] + bmu[n];
            } else if (n < 100) {
                outls[(size_t)m * 50 + (n - 50)] = acc[t][reg] + bls[n - 50];
            }
        }
    }
}

extern "C" void kernel_launch(void* const* d_in, const int* in_sizes, int n_in,
                              void* d_out, int out_size, void* d_ws, size_t ws_size,
                              hipStream_t stream)
{
    const float* x   = (const float*)d_in[0];
    const int*   ei  = (const int*)d_in[1];
    const float* W1  = (const float*)d_in[2];
    const float* b1  = (const float*)d_in[3];
    const float* Wmu = (const float*)d_in[4];
    const float* bmu = (const float*)d_in[5];
    const float* Wls = (const float*)d_in[6];
    const float* bls = (const float*)d_in[7];
    float* out = (float*)d_out;

    const int* src = ei;
    const int* dst = ei + NE;

    // workspace layout (4B element offsets) — round-2 verified layout
    int*   wsI  = (int*)d_ws;
    float* wsF  = (float*)d_ws;
    int*      off  = wsI + 100000;                // 100001 -> pad 200064
    float*    dis  = wsF + 200704;                // 100000
    uint_t*   Wt1g = (uint_t*)(wsI + 300704);     // 7168
    uint_t*   Wt2g = (uint_t*)(wsI + 307872);     // 7168 -> 315040
    int*      bcnt = wsI + 315040;                // 196 pad 256 -> 315296
    int*      ssrc = wsI + 315296;                // 800000 -> 1115296
    int*      bedge= wsI + 1115296;               // 196*6144 = 1204224 -> 2319520
    ushort_t* H1b  = (ushort_t*)(wsI + 2319520);  // 100000*128 bf16 = 6.4M ints -> 8719520
    ushort_t* hb   = (ushort_t*)(wsI + 8719520);  // 6.4M ints -> 15119520
    (void)ws_size;

    hipMemsetAsync(bcnt, 0, 256 * sizeof(int), stream);
    k_part<<<NPART + PACKBLK, 256, 0, stream>>>(src, dst, bcnt, bedge,
                                                W1, Wmu, Wls, Wt1g, Wt2g);
    k_build<<<NBLK, 256, 0, stream>>>(bcnt, bedge, dis, off, ssrc);

    const int gblk = (NN + 63) / 64;
    const int ablk = (NN * 8 + 255) / 256;
    // layer 1: H1' = bf16(X@W1 * dis) ; hb = bf16(relu(dis*(sum H1') + b1) * dis)
    k_gemm1_mfma<<<gblk, 256, 0, stream>>>(x, Wt1g, dis, H1b);
    k_agg1<<<ablk, 256, 0, stream>>>(H1b, off, ssrc, dis, b1, hb);
    // layer 2 (fused): A2 = bf16(dis*(sum hb)) in LDS ; out = A2@[Wmu|Wls] + bias
    k_fuse2<<<gblk, 256, 0, stream>>>(hb, off, ssrc, dis, Wt2g, bmu, bls,
                                      out, out + (size_t)NN * 50);
}

// Round 16
// 233.252 us; speedup vs baseline: 1.3461x; 1.0575x over previous
//
#include <hip/hip_runtime.h>

#define NN 100000
#define NE 800000
#define NBLK 196    // ceil(100000/512): scan blocks AND dst-buckets (512 nodes each)
#define BCAP 6144   // bucket capacity (mean 4081, sigma ~64)
#define EPB 2048    // edges per k_part block (small -> 391 blocks, full CU coverage)
#define NPART ((NE + EPB - 1) / EPB)   // 391
#define PACKBLK 56  // 224*64 threads / 256

typedef unsigned short ushort_t;
typedef unsigned int uint_t;
typedef __attribute__((ext_vector_type(8))) short short8;
typedef __attribute__((ext_vector_type(4))) float floatx4;

__device__ __forceinline__ float bf2f(ushort_t u) {
    union { unsigned int i; float f; } v; v.i = ((unsigned int)u) << 16; return v.f;
}
__device__ __forceinline__ ushort_t f2bf(float f) {
    union { float f; unsigned int i; } v; v.f = f;
    unsigned int b = v.i + 0x7FFF + ((v.i >> 16) & 1);
    return (ushort_t)(b >> 16);
}
__device__ __forceinline__ uint_t pack2(float a, float b) {
    return (uint_t)f2bf(a) | ((uint_t)f2bf(b) << 16);
}

// ---------------- partition edges into 196 dst-buckets (+ fused one-shot W pack) ------------
// record = src | (dstLocal<<17)   (src < 2^17, dstLocal < 512)
__global__ __launch_bounds__(256) void k_part(const int* __restrict__ src,
                                              const int* __restrict__ dst,
                                              int* __restrict__ bcnt,
                                              int* __restrict__ bedge,
                                              const float* __restrict__ W1,
                                              const float* __restrict__ Wmu,
                                              const float* __restrict__ Wls,
                                              uint_t* __restrict__ Wt1g,
                                              uint_t* __restrict__ Wt2g) {
    __shared__ int hist[NBLK];
    __shared__ int lbase[NBLK];
    const int blk = blockIdx.x, t = threadIdx.x;

    if (blk >= NPART) {
        // ---- packW tail blocks: 56 blocks x 256 = 224 (mat,n) groups x 64 kp ----
        int lidx = (blk - NPART) * 256 + t;
        int np = lidx >> 6;            // 0..223
        int kp = lidx & 63;
        int mat = np / 112, n = np - mat * 112;
        int k0 = kp * 2, k1 = k0 + 1;
        float w0 = 0.0f, w1 = 0.0f;
        if (mat == 0) {
            if (n < 100) {
                if (k0 < 100) w0 = W1[k0 * 100 + n];
                if (k1 < 100) w1 = W1[k1 * 100 + n];
            }
            Wt1g[n * 64 + kp] = pack2(w0, w1);
        } else {
            if (n < 50) {
                if (k0 < 100) w0 = Wmu[k0 * 50 + n];
                if (k1 < 100) w1 = Wmu[k1 * 50 + n];
            } else if (n < 100) {
                if (k0 < 100) w0 = Wls[k0 * 50 + (n - 50)];
                if (k1 < 100) w1 = Wls[k1 * 50 + (n - 50)];
            }
            Wt2g[n * 64 + kp] = pack2(w0, w1);
        }
        return;
    }

    const int e0 = blk * EPB;
    const int e1 = (e0 + EPB < NE) ? e0 + EPB : NE;

    if (t < NBLK) hist[t] = 0;
    __syncthreads();
    for (int e = e0 + t; e < e1; e += 256)
        atomicAdd(&hist[dst[e] >> 9], 1);
    __syncthreads();
    if (t < NBLK) {
        int h = hist[t];
        lbase[t] = (h > 0) ? atomicAdd(&bcnt[t], h) : 0;
    }
    __syncthreads();
    if (t < NBLK) hist[t] = lbase[t];   // reuse as cursor
    __syncthreads();
    for (int e = e0 + t; e < e1; e += 256) {
        int d = dst[e];
        int b = d >> 9;
        int pos = atomicAdd(&hist[b], 1);
        bedge[b * BCAP + pos] = src[e] | ((d & 511) << 17);
    }
}

// ---------------- fused per-bucket build (512 threads): hist + base + scan + place ---------
__global__ __launch_bounds__(512) void k_build(const int* __restrict__ bcnt,
                                               const int* __restrict__ bedge,
                                               float* __restrict__ dis,
                                               int* __restrict__ off,
                                               int* __restrict__ ssrc) {
    __shared__ int eb[BCAP];       // 24 KB: bucket edges staged once
    __shared__ int hist[512];      // degree hist, later place cursors
    __shared__ int sc[2][512];     // scan ping-pong
    __shared__ int red[8];
    const int b = blockIdx.x, t = threadIdx.x;
    const int cnt = bcnt[b];
    const int* be = bedge + (size_t)b * BCAP;
    const int g0 = b * 512;

    hist[t] = 0;
    // base = sum bcnt[0..b)  (b <= 195 < 512, thread t holds bcnt[t] iff t < b)
    int part = (t < b) ? bcnt[t] : 0;
    #pragma unroll
    for (int o = 32; o > 0; o >>= 1) part += __shfl_down(part, o, 64);
    if ((t & 63) == 0) red[t >> 6] = part;
    __syncthreads();

    // stage edges to LDS + degree histogram in one pass over bedge
    for (int i = t; i < cnt; i += 512) {
        int v = be[i];
        eb[i] = v;
        atomicAdd(&hist[v >> 17], 1);
    }
    __syncthreads();
    int base0 = 0;
    #pragma unroll
    for (int r = 0; r < 8; ++r) base0 += red[r];

    // inclusive scan of 512 degrees (1 elem/thread)
    sc[0][t] = hist[t];
    __syncthreads();
    int c = 0;
    for (int o = 1; o < 512; o <<= 1) {
        int nxt = c ^ 1;
        sc[nxt][t] = sc[c][t] + ((t >= o) ? sc[c][t - o] : 0);
        c = nxt;
        __syncthreads();
    }

    // emit dis + off, init place cursors (hist[t] exclusively owned by this thread)
    {
        int g = g0 + t;
        int ov = base0 + ((t > 0) ? sc[c][t - 1] : 0);
        if (g < NN) dis[g] = rsqrtf((float)hist[t] + 1.0f);
        if (g <= NN) off[g] = ov;
        hist[t] = ov;
    }
    __syncthreads();

    // place edges from LDS into contiguous CSR region
    for (int i = t; i < cnt; i += 512) {
        int v = eb[i];
        int pos = atomicAdd(&hist[v >> 17], 1);
        ssrc[pos] = v & 0x1FFFF;
    }
}

// ---------------- MFMA GEMM 1: H1' = bf16((X @ W1) * dis), stride 128, pads zeroed ----------
__global__ __launch_bounds__(256) void k_gemm1_mfma(
    const float* __restrict__ X, const uint_t* __restrict__ Wtg,
    const float* __restrict__ dis,
    ushort_t* __restrict__ H)
{
    __shared__ ushort_t Ws[112 * 136];   // 30.5 KB
    const int tid = threadIdx.x;
    const int row0 = blockIdx.x * 64;

    for (int idx = tid; idx < 112 * 16; idx += 256) {
        int n = idx >> 4, c = idx & 15;
        uint4 v = *(const uint4*)&Wtg[n * 64 + c * 4];
        *(uint4*)&Ws[n * 136 + c * 8] = v;
    }
    __syncthreads();

    const int wave = tid >> 6, lane = tid & 63;
    const int quad = lane >> 4, l16 = lane & 15;
    int row = row0 + wave * 16 + l16;
    if (row >= NN) row = NN - 1;
    const float* xp = X + (size_t)row * 100;

    floatx4 acc[7];
    #pragma unroll
    for (int t = 0; t < 7; ++t) acc[t] = (floatx4){0.f, 0.f, 0.f, 0.f};

    #pragma unroll
    for (int ks = 0; ks < 4; ++ks) {
        const int kb = ks * 32 + quad * 8;
        short8 af;
        if (ks < 3) {
            float4 u = *(const float4*)&xp[kb];
            float4 v = *(const float4*)&xp[kb + 4];
            af[0] = (short)f2bf(u.x); af[1] = (short)f2bf(u.y);
            af[2] = (short)f2bf(u.z); af[3] = (short)f2bf(u.w);
            af[4] = (short)f2bf(v.x); af[5] = (short)f2bf(v.y);
            af[6] = (short)f2bf(v.z); af[7] = (short)f2bf(v.w);
        } else {
            af = (short8){0, 0, 0, 0, 0, 0, 0, 0};
            if (quad == 0) {
                float4 u = *(const float4*)&xp[96];
                af[0] = (short)f2bf(u.x); af[1] = (short)f2bf(u.y);
                af[2] = (short)f2bf(u.z); af[3] = (short)f2bf(u.w);
            }
        }
        #pragma unroll
        for (int t = 0; t < 7; ++t) {
            short8 bf = *(const short8*)&Ws[(t * 16 + l16) * 136 + kb];
            acc[t] = __builtin_amdgcn_mfma_f32_16x16x32_bf16(af, bf, acc[t], 0, 0, 0);
        }
    }

    const int mbase = row0 + wave * 16 + quad * 4;
    #pragma unroll
    for (int reg = 0; reg < 4; ++reg) {
        int m = mbase + reg;
        if (m >= NN) continue;
        float dd = dis[m];
        #pragma unroll
        for (int t = 0; t < 7; ++t) {
            int n = t * 16 + l16;
            H[(size_t)m * 128 + n] = (n < 100) ? f2bf(acc[t][reg] * dd) : (ushort_t)0;
        }
        H[(size_t)m * 128 + 112 + l16] = 0;
    }
}

// ---------------- aggregation phase 1 (round-2 proven form: 8 threads/node) ----------------
// val = dis[node] * (H'[node] + sum_e H'[src]);  store bf16(relu(val + b1) * dis[node])
__global__ __launch_bounds__(256) void k_agg1(
    const ushort_t* __restrict__ Hin,
    const int* __restrict__ off, const int* __restrict__ ssrc,
    const float* __restrict__ dis, const float* __restrict__ bias,
    ushort_t* __restrict__ outb)
{
    int i = blockIdx.x * 256 + threadIdx.x;
    if (i >= NN * 8) return;
    int node = i >> 3;
    int col = (i & 7) * 16;

    float a[16];
    {
        short8 u = *(const short8*)(Hin + (size_t)node * 128 + col);
        short8 v = *(const short8*)(Hin + (size_t)node * 128 + col + 8);
        #pragma unroll
        for (int j = 0; j < 8; ++j) { a[j] = bf2f((ushort_t)u[j]); a[8 + j] = bf2f((ushort_t)v[j]); }
    }

    int e0 = off[node], e1 = off[node + 1];
    int e = e0;
    for (; e + 3 < e1; e += 4) {
        int s0 = ssrc[e], s1 = ssrc[e + 1], s2 = ssrc[e + 2], s3 = ssrc[e + 3];
        short8 u0 = *(const short8*)(Hin + (size_t)s0 * 128 + col);
        short8 v0 = *(const short8*)(Hin + (size_t)s0 * 128 + col + 8);
        short8 u1 = *(const short8*)(Hin + (size_t)s1 * 128 + col);
        short8 v1 = *(const short8*)(Hin + (size_t)s1 * 128 + col + 8);
        short8 u2 = *(const short8*)(Hin + (size_t)s2 * 128 + col);
        short8 v2 = *(const short8*)(Hin + (size_t)s2 * 128 + col + 8);
        short8 u3 = *(const short8*)(Hin + (size_t)s3 * 128 + col);
        short8 v3 = *(const short8*)(Hin + (size_t)s3 * 128 + col + 8);
        #pragma unroll
        for (int j = 0; j < 8; ++j) {
            a[j]     += bf2f((ushort_t)u0[j]) + bf2f((ushort_t)u1[j])
                      + bf2f((ushort_t)u2[j]) + bf2f((ushort_t)u3[j]);
            a[8 + j] += bf2f((ushort_t)v0[j]) + bf2f((ushort_t)v1[j])
                      + bf2f((ushort_t)v2[j]) + bf2f((ushort_t)v3[j]);
        }
    }
    for (; e < e1; ++e) {
        int s0 = ssrc[e];
        short8 u0 = *(const short8*)(Hin + (size_t)s0 * 128 + col);
        short8 v0 = *(const short8*)(Hin + (size_t)s0 * 128 + col + 8);
        #pragma unroll
        for (int j = 0; j < 8; ++j) {
            a[j] += bf2f((ushort_t)u0[j]);
            a[8 + j] += bf2f((ushort_t)v0[j]);
        }
    }

    float d = dis[node];
    short8 o0, o1;
    float b[16];
    #pragma unroll
    for (int j = 0; j < 16; ++j) {
        int cj = col + j;
        b[j] = (cj < 100) ? bias[cj] : 0.0f;
    }
    #pragma unroll
    for (int j = 0; j < 8; ++j) {
        float h0 = fmaxf(a[j] * d + b[j], 0.0f) * d;
        float h1 = fmaxf(a[8 + j] * d + b[8 + j], 0.0f) * d;
        o0[j] = (short)f2bf(h0);
        o1[j] = (short)f2bf(h1);
    }
    *(short8*)(outb + (size_t)node * 128 + col) = o0;
    *(short8*)(outb + (size_t)node * 128 + col + 8) = o1;
}

// ---------------- FUSED agg2 + gemm2 v2: 32 nodes/block, 8 threads/node gather -------------
// Gather phase = exact agg1 shape (8 thr/node x 16 cols) -> As[32][136] LDS.
// MFMA phase: waves 0-1 compute out = As @ [Wmu|Wls] + [bmu|bls].
__global__ __launch_bounds__(256) void k_fuse2(
    const ushort_t* __restrict__ Hin,   // hb (complete)
    const int* __restrict__ off, const int* __restrict__ ssrc,
    const float* __restrict__ dis,
    const uint_t* __restrict__ Wtg,
    const float* __restrict__ bmu, const float* __restrict__ bls,
    float* __restrict__ outmu, float* __restrict__ outls)
{
    __shared__ ushort_t Ws[112 * 136];   // 30.5 KB
    __shared__ ushort_t As[32][136];     // 8.5 KB
    const int tid = threadIdx.x;
    const int row0 = blockIdx.x * 32;

    for (int idx = tid; idx < 112 * 16; idx += 256) {
        int n = idx >> 4, c = idx & 15;
        uint4 v = *(const uint4*)&Wtg[n * 64 + c * 4];
        *(uint4*)&Ws[n * 136 + c * 8] = v;
    }

    // ---- gather phase: thread = (local node lr = tid>>3, colgrp = tid&7) ----
    {
        const int lr = tid >> 3;
        const int col = (tid & 7) * 16;   // 0..112
        int nd = row0 + lr;
        if (nd >= NN) nd = NN - 1;        // duplicate last row; out-write is guarded

        float a[16];
        {
            short8 u = *(const short8*)(Hin + (size_t)nd * 128 + col);
            short8 v = *(const short8*)(Hin + (size_t)nd * 128 + col + 8);
            #pragma unroll
            for (int j = 0; j < 8; ++j) { a[j] = bf2f((ushort_t)u[j]); a[8 + j] = bf2f((ushort_t)v[j]); }
        }

        int e0 = off[nd], e1 = off[nd + 1];
        int e = e0;
        for (; e + 3 < e1; e += 4) {
            int s0 = ssrc[e], s1 = ssrc[e + 1], s2 = ssrc[e + 2], s3 = ssrc[e + 3];
            short8 u0 = *(const short8*)(Hin + (size_t)s0 * 128 + col);
            short8 v0 = *(const short8*)(Hin + (size_t)s0 * 128 + col + 8);
            short8 u1 = *(const short8*)(Hin + (size_t)s1 * 128 + col);
            short8 v1 = *(const short8*)(Hin + (size_t)s1 * 128 + col + 8);
            short8 u2 = *(const short8*)(Hin + (size_t)s2 * 128 + col);
            short8 v2 = *(const short8*)(Hin + (size_t)s2 * 128 + col + 8);
            short8 u3 = *(const short8*)(Hin + (size_t)s3 * 128 + col);
            short8 v3 = *(const short8*)(Hin + (size_t)s3 * 128 + col + 8);
            #pragma unroll
            for (int j = 0; j < 8; ++j) {
                a[j]     += bf2f((ushort_t)u0[j]) + bf2f((ushort_t)u1[j])
                          + bf2f((ushort_t)u2[j]) + bf2f((ushort_t)u3[j]);
                a[8 + j] += bf2f((ushort_t)v0[j]) + bf2f((ushort_t)v1[j])
                          + bf2f((ushort_t)v2[j]) + bf2f((ushort_t)v3[j]);
            }
        }
        for (; e < e1; ++e) {
            int s0 = ssrc[e];
            short8 u0 = *(const short8*)(Hin + (size_t)s0 * 128 + col);
            short8 v0 = *(const short8*)(Hin + (size_t)s0 * 128 + col + 8);
            #pragma unroll
            for (int j = 0; j < 8; ++j) {
                a[j] += bf2f((ushort_t)u0[j]);
                a[8 + j] += bf2f((ushort_t)v0[j]);
            }
        }

        const float d = dis[nd];
        short8 o0, o1;
        #pragma unroll
        for (int j = 0; j < 8; ++j) {
            o0[j] = (short)f2bf(a[j] * d);
            o1[j] = (short)f2bf(a[8 + j] * d);
        }
        *(short8*)&As[lr][col] = o0;
        *(short8*)&As[lr][col + 8] = o1;
    }
    __syncthreads();

    // ---- MFMA phase (waves 0-1 cover the 32 rows) ----
    const int wave = tid >> 6, lane = tid & 63;
    if (wave < 2) {
        const int quad = lane >> 4, l16 = lane & 15;
        const int lrow = wave * 16 + l16;

        floatx4 acc[7];
        #pragma unroll
        for (int t = 0; t < 7; ++t) acc[t] = (floatx4){0.f, 0.f, 0.f, 0.f};

        #pragma unroll
        for (int k0 = 0; k0 < 128; k0 += 32) {
            short8 af = *(const short8*)&As[lrow][k0 + quad * 8];
            #pragma unroll
            for (int t = 0; t < 7; ++t) {
                short8 bf = *(const short8*)&Ws[(t * 16 + l16) * 136 + k0 + quad * 8];
                acc[t] = __builtin_amdgcn_mfma_f32_16x16x32_bf16(af, bf, acc[t], 0, 0, 0);
            }
        }

        const int mbase = row0 + wave * 16 + quad * 4;
        #pragma unroll
        for (int reg = 0; reg < 4; ++reg) {
            int m = mbase + reg;
            if (m >= NN) continue;
            #pragma unroll
            for (int t = 0; t < 7; ++t) {
                int n = t * 16 + l16;
                if (n < 50) {
                    outmu[(size_t)m * 50 + n] = acc[t][reg] + bmu[n];
                } else if (n < 100) {
                    outls[(size_t)m * 50 + (n - 50)] = acc[t][reg] + bls[n - 50];
                }
            }
        }
    }
}

extern "C" void kernel_launch(void* const* d_in, const int* in_sizes, int n_in,
                              void* d_out, int out_size, void* d_ws, size_t ws_size,
                              hipStream_t stream)
{
    const float* x   = (const float*)d_in[0];
    const int*   ei  = (const int*)d_in[1];
    const float* W1  = (const float*)d_in[2];
    const float* b1  = (const float*)d_in[3];
    const float* Wmu = (const float*)d_in[4];
    const float* bmu = (const float*)d_in[5];
    const float* Wls = (const float*)d_in[6];
    const float* bls = (const float*)d_in[7];
    float* out = (float*)d_out;

    const int* src = ei;
    const int* dst = ei + NE;

    // workspace layout (4B element offsets) — round-2 verified layout
    int*   wsI  = (int*)d_ws;
    float* wsF  = (float*)d_ws;
    int*      off  = wsI + 100000;                // 100001 -> pad 200064
    float*    dis  = wsF + 200704;                // 100000
    uint_t*   Wt1g = (uint_t*)(wsI + 300704);     // 7168
    uint_t*   Wt2g = (uint_t*)(wsI + 307872);     // 7168 -> 315040
    int*      bcnt = wsI + 315040;                // 196 pad 256 -> 315296
    int*      ssrc = wsI + 315296;                // 800000 -> 1115296
    int*      bedge= wsI + 1115296;               // 196*6144 = 1204224 -> 2319520
    ushort_t* H1b  = (ushort_t*)(wsI + 2319520);  // 100000*128 bf16 = 6.4M ints -> 8719520
    ushort_t* hb   = (ushort_t*)(wsI + 8719520);  // 6.4M ints -> 15119520
    (void)ws_size;

    hipMemsetAsync(bcnt, 0, 256 * sizeof(int), stream);
    k_part<<<NPART + PACKBLK, 256, 0, stream>>>(src, dst, bcnt, bedge,
                                                W1, Wmu, Wls, Wt1g, Wt2g);
    k_build<<<NBLK, 512, 0, stream>>>(bcnt, bedge, dis, off, ssrc);

    const int gblk = (NN + 63) / 64;
    const int ablk = (NN * 8 + 255) / 256;
    const int fblk = (NN + 31) / 32;
    // layer 1: H1' = bf16(X@W1 * dis) ; hb = bf16(relu(dis*(sum H1') + b1) * dis)
    k_gemm1_mfma<<<gblk, 256, 0, stream>>>(x, Wt1g, dis, H1b);
    k_agg1<<<ablk, 256, 0, stream>>>(H1b, off, ssrc, dis, b1, hb);
    // layer 2 (fused): A2 = bf16(dis*(sum hb)) in LDS ; out = A2@[Wmu|Wls] + bias
    k_fuse2<<<fblk, 256, 0, stream>>>(hb, off, ssrc, dis, Wt2g, bmu, bls,
                                      out, out + (size_t)NN * 50);
}